// Round 16
// baseline (2335.206 us; speedup 1.0000x reference)
//
#include <hip/hip_runtime.h>

#define NT_TOK 32768
#define DM 1024
#define DH 4096
#define NE 8
#define BT 256          /* segment padding quantum */
#define BM 128          /* tile M */
#define BN 128          /* tile N */
#define BK 32           /* K-tile (ring-3) */
#define CAP (NT_TOK*2 + NE*BT)   /* 67584 padded assignment capacity */
#define CHUNK_ROWS 32768

typedef _Float16 f16x8 __attribute__((ext_vector_type(8)));
typedef float f32x4 __attribute__((ext_vector_type(4)));
typedef float f32x8 __attribute__((ext_vector_type(8)));

__device__ __forceinline__ unsigned short f2h_bits(float v){
  _Float16 h = (_Float16)v;
  return __builtin_bit_cast(unsigned short, h);
}

__device__ __forceinline__ void async16(const void* g, void* l){
  __builtin_amdgcn_global_load_lds((const __attribute__((address_space(1))) void*)g,
                                   (__attribute__((address_space(3))) void*)l, 16, 0, 0);
}

// bijective XCD-aware remap (m204 variant)
__device__ __forceinline__ int xcd_remap(int orig, int nwg){
  int q = nwg >> 3, r = nwg & 7;
  int x = orig & 7, i = orig >> 3;
  int base = (x < r) ? x*(q+1) : r*(q+1) + (x-r)*q;
  return base + i;
}

// ---------------- prep kernels ----------------

__global__ __launch_bounds__(256) void cvt_f16_kernel(const float* __restrict__ src,
                                                      unsigned short* __restrict__ dst, int n8){
  int i = blockIdx.x*256 + threadIdx.x;
  if (i >= n8) return;
  float4 a = ((const float4*)src)[2*i];
  float4 b = ((const float4*)src)[2*i+1];
  union { unsigned short u[8]; uint4 v; } r;
  r.u[0]=f2h_bits(a.x); r.u[1]=f2h_bits(a.y); r.u[2]=f2h_bits(a.z); r.u[3]=f2h_bits(a.w);
  r.u[4]=f2h_bits(b.x); r.u[5]=f2h_bits(b.y); r.u[6]=f2h_bits(b.z); r.u[7]=f2h_bits(b.w);
  ((uint4*)dst)[i] = r.v;
}

// src [E][R][C] f32 -> dst [E][C][R] f16 ; 64x64 tiles, float4 reads, 8B f16 writes
__global__ __launch_bounds__(256) void transpose_f16_v2(const float* __restrict__ src,
    unsigned short* __restrict__ dst, int R, int C){
  __shared__ float t[64][65];
  int ez = blockIdx.z;
  const float* s = src + (size_t)ez*R*C;
  unsigned short* d = dst + (size_t)ez*R*C;
  int c0 = blockIdx.x*64, r0 = blockIdx.y*64;
  int tx = threadIdx.x & 15, ty = threadIdx.x >> 4;
  #pragma unroll
  for (int i=0;i<4;i++){
    float4 v = *(const float4*)&s[(size_t)(r0+ty+i*16)*C + c0 + tx*4];
    t[ty+i*16][tx*4+0]=v.x; t[ty+i*16][tx*4+1]=v.y;
    t[ty+i*16][tx*4+2]=v.z; t[ty+i*16][tx*4+3]=v.w;
  }
  __syncthreads();
  #pragma unroll
  for (int i=0;i<4;i++){
    int cc = ty + i*16;                       // src col -> dst row (c0+cc)
    union { unsigned short u[4]; uint2 v; } o;
    #pragma unroll
    for (int j=0;j<4;j++) o.u[j] = f2h_bits(t[tx*4+j][cc]);
    *(uint2*)&d[(size_t)(c0+cc)*R + r0 + tx*4] = o.v;
  }
}

// ---------------- router (f64 accumulate -> top-2 selection matches np ref) ----------------

__global__ __launch_bounds__(256) void router_kernel(const float* __restrict__ x,
    const float* __restrict__ Wr, const float* __restrict__ br,
    int* __restrict__ topi, float* __restrict__ topw, int* __restrict__ counts){
  __shared__ float wr_s[NE*DM];
  __shared__ int bcnt[NE];
  int tid = threadIdx.x;
  if (tid < NE) bcnt[tid] = 0;
  for (int idx=tid; idx<NE*DM; idx+=256){
    int k = idx>>3, e = idx&7;
    wr_s[e*DM + k] = Wr[idx];
  }
  __syncthreads();
  int w = tid>>6, lane = tid&63;
  for (int tt=0; tt<16; ++tt){
    int t = blockIdx.x*64 + w*16 + tt;
    const float* xr = x + (size_t)t*DM;
    double acc[NE];
    #pragma unroll
    for (int e=0;e<NE;e++) acc[e]=0.0;
    #pragma unroll
    for (int j=0;j<16;j++){
      float xv = xr[j*64 + lane];
      #pragma unroll
      for (int e=0;e<NE;e++) acc[e] += (double)xv * (double)wr_s[e*DM + j*64 + lane];
    }
    #pragma unroll
    for (int e=0;e<NE;e++){
      #pragma unroll
      for (int d=32; d; d>>=1) acc[e] += __shfl_xor(acc[e], d);
    }
    if (lane==0){
      double l[NE];
      #pragma unroll
      for (int e=0;e<NE;e++) l[e] = acc[e] + (double)br[e];
      int i0 = 0;
      #pragma unroll
      for (int e=1;e<NE;e++) if (l[e] > l[i0]) i0 = e;
      int i1 = (i0==0) ? 1 : 0;
      #pragma unroll
      for (int e=0;e<NE;e++) if (e != i0 && l[e] > l[i1]) i1 = e;
      double w0 = 1.0/(1.0 + exp(l[i1]-l[i0]));   // renormalized top-2 softmax, exact identity
      topi[2*t] = i0; topi[2*t+1] = i1;
      topw[2*t] = (float)w0; topw[2*t+1] = (float)(1.0-w0);
      atomicAdd(&bcnt[i0],1); atomicAdd(&bcnt[i1],1);   // LDS atomics
    }
  }
  __syncthreads();
  if (tid < NE && bcnt[tid] > 0) atomicAdd(&counts[tid], bcnt[tid]);
}

__global__ void offsets_kernel(const int* __restrict__ counts, int* __restrict__ off){
  if (threadIdx.x==0 && blockIdx.x==0){
    int o = 0;
    for (int e=0;e<NE;e++){ off[e] = o; o += ((counts[e]+BT-1)/BT)*BT; }
    off[NE] = o;
  }
}

// hierarchical scatter: LDS intra-block rank + one global atomic per expert per block
__global__ __launch_bounds__(256) void scatter_kernel(const int* __restrict__ topi,
    const float* __restrict__ topw, const int* __restrict__ off,
    int* __restrict__ cursor, int* __restrict__ atok, float* __restrict__ awgt){
  __shared__ int bcnt[NE];
  __shared__ int bbase[NE];
  int tid = threadIdx.x;
  if (tid < NE) bcnt[tid] = 0;
  __syncthreads();
  int t = blockIdx.x*256 + tid;
  int e0 = topi[2*t],   e1 = topi[2*t+1];
  int r0 = atomicAdd(&bcnt[e0], 1);
  int r1 = atomicAdd(&bcnt[e1], 1);
  __syncthreads();
  if (tid < NE) bbase[tid] = (bcnt[tid] > 0) ? atomicAdd(&cursor[tid], bcnt[tid]) : 0;
  __syncthreads();
  int s0 = off[e0] + bbase[e0] + r0;
  int s1 = off[e1] + bbase[e1] + r1;
  atok[s0] = t;  awgt[s0] = topw[2*t];
  atok[s1] = t;  awgt[s1] = topw[2*t+1];
}

// ---------------- 128x128 4-wave GEMM core (R11 pipeline at 12 waves/CU) -------------------
// The one untested principled config: m97's occupancy point (3 blocks/CU x 4 waves = 12
// waves/CU; 64-AGPR acc + <=168 regs + 48KB ring-3 LDS) COMBINED with the verified R11
// counted-vmcnt ring pipeline. Inter-block TLP absorbs the vmcnt/barrier stalls that no
// intra-block schedule could hide (R5-R14 all 8 waves/CU, all ~24% MfmaUtil).
// Block order: mt-FASTEST within each XCD chunk (nt = wg/mtc) -> each XCD runs all m-tiles
// of one 128-col B-panel consecutively => B L2-resident (fixes R10's FETCH explosion).
// Ring-3: tile t in buf[t%3]; stage t+2 during t (A phase 0, B phase 1; 4 instr/tile).
// Top-of-tile: outstanding {t,t+1} = 8 -> vmcnt(4) drains tile t (oldest-first, m135);
// tail vmcnt(0). buf(t+2)=buf(t-1), freed at t's top barrier.
// LDS slot map (R11-verified, 0 conflicts): slot(r,kc)=(r>>1)*8+((kc+4*(r&1))^((r>>1)&7))

template<int KDIM, bool IS_G2>
__global__ __launch_bounds__(256, 3) void gemm_big_kernel(
    const unsigned short* __restrict__ Asrc,    // XB (g1) or Hb (g2)
    const unsigned short* __restrict__ WT,      // W1T (g1) or W2T (g2), [E][N][K] f16
    const float* __restrict__ bias,             // b1 or b2
    const int* __restrict__ atok,
    const float* __restrict__ awgt,
    const int* __restrict__ offs,
    unsigned short* __restrict__ H,             // g1 out
    float* __restrict__ out,                    // g2 out
    int c0, int mtc){
  __shared__ unsigned short As[3][BM*BK];       // 3 x 8 KB
  __shared__ unsigned short Bs[3][BN*BK];       // 3 x 8 KB
  const int NDIM = IS_G2 ? DM : DH;
  int wg = xcd_remap(blockIdx.x, gridDim.x);
  int nt = wg / mtc, mt = wg - nt*mtc;          // mt-fastest: consecutive wg share B panel
  int total = offs[NE];
  int m0 = c0 + mt*BM;
  if (m0 >= total) return;
  int e = 0;
  #pragma unroll
  for (int q=0;q<NE-1;q++) if (m0 >= offs[q+1]) e = q+1;
  int tid = threadIdx.x;
  int lane = tid&63, wid = tid>>6;
  int wm = wid>>1, wn = wid&1;                  // 2x2 waves; per-wave out 64x64

  // staging: slot c = j*256+tid (j<2) holds G[srow][schunk]:
  //   u=(c&7)^((c>>3)&7); srow=2*(c>>3)+(u>>2); schunk=u&3   (128 rows x 4 chunks)
  const unsigned short* agp[2];
  const unsigned short* bgp[2];
  int dofs[2];
  #pragma unroll
  for (int j=0;j<2;j++){
    int c = j*256 + tid;
    int u = (c&7) ^ ((c>>3)&7);
    int srow = ((c>>3)<<1) + (u>>2);
    int sch  = u&3;
    if (IS_G2){
      agp[j] = Asrc + (size_t)(m0 - c0 + srow)*KDIM + sch*8;
    } else {
      int tok = atok[m0 + srow];
      if (tok < 0) tok = 0;                 // pad rows: safe dummy gather
      agp[j] = Asrc + (size_t)tok*KDIM + sch*8;
    }
    bgp[j] = WT + ((size_t)e*NDIM + nt*BN + srow)*KDIM + sch*8;
    dofs[j] = c*8;                          // element offset of 16B slot c
  }

  // read offsets: elem = (r>>1)*64 + ((kc + 4*(r&1)) ^ ((r>>1)&7))*8 ; +512 per 16 rows
  int pos = (((lane>>4) + ((lane&1)<<2)) ^ ((lane>>1)&7)) << 3;
  int aoff0 = (wm*32 + ((lane&15)>>1))*64 + pos;
  int boff0 = (wn*32 + ((lane&15)>>1))*64 + pos;

  f32x4 acc[4][4];
  #pragma unroll
  for (int i=0;i<4;i++)
    #pragma unroll
    for (int j=0;j<4;j++) acc[i][j] = 0.0f;

  const int NKT = KDIM/BK;
  // prologue: prime tiles 0,1 (per tile A then B — matches in-loop order)
  #pragma unroll
  for (int t=0;t<2;t++){
    #pragma unroll
    for (int j=0;j<2;j++) async16(agp[j] + t*BK, &As[t][dofs[j]]);
    #pragma unroll
    for (int j=0;j<2;j++) async16(bgp[j] + t*BK, &Bs[t][dofs[j]]);
  }

  int cur = 0;
  for (int kt=0; kt<NKT; ++kt){
    if (kt < NKT-1) asm volatile("s_waitcnt vmcnt(4)" ::: "memory");
    else            asm volatile("s_waitcnt vmcnt(0)" ::: "memory");
    __builtin_amdgcn_s_barrier();
    int nxt2 = cur + 2; if (nxt2 >= 3) nxt2 -= 3;
    const unsigned short* Ab = &As[cur][0];
    const unsigned short* Bb = &Bs[cur][0];
    f16x8 b[4], a[4];
    #pragma unroll
    for (int nf=0;nf<4;nf++) b[nf] = *(const f16x8*)&Bb[boff0 + nf*512];
    #pragma unroll
    for (int mf=0;mf<4;mf++) a[mf] = *(const f16x8*)&Ab[aoff0 + mf*512];
    if (kt+2 < NKT){
      #pragma unroll
      for (int j=0;j<2;j++) async16(agp[j] + (size_t)(kt+2)*BK, &As[nxt2][dofs[j]]);
    }
    __builtin_amdgcn_s_setprio(1);
    #pragma unroll
    for (int mf=0;mf<4;mf++)
      #pragma unroll
      for (int nf=0;nf<2;nf++)
        acc[mf][nf] = __builtin_amdgcn_mfma_f32_16x16x32_f16(a[mf], b[nf], acc[mf][nf], 0,0,0);
    __builtin_amdgcn_s_setprio(0);
    __builtin_amdgcn_s_barrier();           // mid-tile (R7/R8-measured win)
    if (kt+2 < NKT){
      #pragma unroll
      for (int j=0;j<2;j++) async16(bgp[j] + (size_t)(kt+2)*BK, &Bs[nxt2][dofs[j]]);
    }
    __builtin_amdgcn_s_setprio(1);
    #pragma unroll
    for (int mf=0;mf<4;mf++)
      #pragma unroll
      for (int nf=2;nf<4;nf++)
        acc[mf][nf] = __builtin_amdgcn_mfma_f32_16x16x32_f16(a[mf], b[nf], acc[mf][nf], 0,0,0);
    __builtin_amdgcn_s_setprio(0);
    cur = (cur + 1 == 3) ? 0 : cur + 1;
  }

  // epilogue (verified C mapping)
  int nbase = nt*BN + wn*64 + (lane&15);
  if (!IS_G2){
    const float* be = bias + (size_t)e*DH;
    int rloc = (m0 - c0) + wm*64 + ((lane>>4)<<2);
    #pragma unroll
    for (int mf=0;mf<4;mf++)
      #pragma unroll
      for (int nf=0;nf<4;nf++){
        int nn = nbase + nf*16;
        float bv = be[nn];
        #pragma unroll
        for (int r2=0;r2<4;r2++){
          float v = acc[mf][nf][r2] + bv;
          float g = 0.5f*v*(1.0f + erff(v*0.70710678118654752f));
          H[(size_t)(rloc + mf*16 + r2)*DH + nn] = f2h_bits(g);
        }
      }
  } else {
    const float* be = bias + (size_t)e*DM;
    int sbase = m0 + wm*64 + ((lane>>4)<<2);
    #pragma unroll
    for (int mf=0;mf<4;mf++){
      #pragma unroll
      for (int r2=0;r2<4;r2++){
        int slot = sbase + mf*16 + r2;
        int tok = atok[slot];
        float wgt = awgt[slot];
        if (tok >= 0){
          #pragma unroll
          for (int nf=0;nf<4;nf++){
            int nn = nbase + nf*16;
            float v = acc[mf][nf][r2] + be[nn];
            atomicAdd(&out[(size_t)tok*DM + nn], wgt*v);
          }
        }
      }
    }
  }
}

// ---------------- GEMM1 fallback (A staged from f32 x, no XB; 128x128 tile) ----------------

__global__ __launch_bounds__(256) void gemm1_f32_kernel(
    const float* __restrict__ xf, const unsigned short* __restrict__ W1T,
    const float* __restrict__ b1, const int* __restrict__ atok,
    const int* __restrict__ offs, unsigned short* __restrict__ H, int c0){
  __shared__ float Asf[128*64];
  __shared__ unsigned short Bsld[128*64];
  const int NT = DH/128;
  int wg = xcd_remap(blockIdx.x, gridDim.x);
  int nt = wg % NT, mt = wg / NT;
  int total = offs[NE];
  int m0 = c0 + mt*128;
  if (m0 >= total) return;
  int e = 0;
  #pragma unroll
  for (int q=0;q<NE-1;q++) if (m0 >= offs[q+1]) e = q+1;
  int tid = threadIdx.x;
  const void* ag[8];
  int aofs[8];
  #pragma unroll
  for (int j=0;j<8;j++){
    int c = j*256 + tid;
    int r = c>>4, sb = (c&15)*16;
    int tok = atok[m0 + r];
    if (tok < 0) tok = 0;
    ag[j] = (const void*)((const char*)(xf + (size_t)tok*DM) + sb);
    aofs[j] = c*16;
  }
  const unsigned short* bg[4];
  int bofs[4];
  #pragma unroll
  for (int j=0;j<4;j++){
    int c = j*256 + tid;
    int r = c>>3, s = c&7;
    bg[j] = W1T + ((size_t)e*DH + nt*128 + r)*DM + s*8;
    bofs[j] = c*16;
  }
  f32x4 acc[4][4];
  #pragma unroll
  for (int i=0;i<4;i++)
    #pragma unroll
    for (int j=0;j<4;j++) acc[i][j] = 0.0f;
  int lane = tid&63;
  int wm = tid>>7, wn = (tid>>6)&1;
  int arow = wm*64 + (lane&15);
  int ak0  = (lane>>4)*8;
  int brr  = (wn*64 + (lane&15))*64 + ak0;
  for (int kt=0; kt<DM/64; ++kt){
    #pragma unroll
    for (int j=0;j<8;j++)
      async16((const char*)ag[j] + (size_t)kt*64*4, (char*)Asf + aofs[j]);
    #pragma unroll
    for (int j=0;j<4;j++)
      async16(bg[j] + (size_t)kt*64, (char*)Bsld + bofs[j]);
    __syncthreads();
    #pragma unroll
    for (int kk=0; kk<64; kk+=32){
      f16x8 a[4], b[4];
      #pragma unroll
      for (int f=0;f<4;f++){
        f32x8 v = *(const f32x8*)&Asf[(arow + f*16)*64 + ak0 + kk];
        a[f] = __builtin_convertvector(v, f16x8);
        b[f] = *(const f16x8*)&Bsld[brr + f*16*64 + kk];
      }
      #pragma unroll
      for (int i=0;i<4;i++)
        #pragma unroll
        for (int j2=0;j2<4;j2++)
          acc[i][j2] = __builtin_amdgcn_mfma_f32_16x16x32_f16(a[i], b[j2], acc[i][j2], 0,0,0);
    }
    __syncthreads();
  }
  const float* b1e = b1 + (size_t)e*DH;
  int rloc = (m0 - c0) + wm*64 + ((lane>>4)<<2);
  int nbase = nt*128 + wn*64 + (lane&15);
  #pragma unroll
  for (int i=0;i<4;i++)
    #pragma unroll
    for (int j=0;j<4;j++){
      int nn = nbase + j*16;
      float bv = b1e[nn];
      #pragma unroll
      for (int r2=0;r2<4;r2++){
        float v = acc[i][j][r2] + bv;
        float g = 0.5f*v*(1.0f + erff(v*0.70710678118654752f));
        H[(size_t)(rloc + i*16 + r2)*DH + nn] = f2h_bits(g);
      }
    }
}

__global__ void fill_kernel(float* p, float v, size_t n){
  size_t i = (size_t)blockIdx.x*256 + threadIdx.x;
  if (i < n) p[i] = v;
}

// ---------------- launch ----------------

extern "C" void kernel_launch(void* const* d_in, const int* in_sizes, int n_in,
                              void* d_out, int out_size, void* d_ws, size_t ws_size,
                              hipStream_t stream){
  const float* x  = (const float*)d_in[0];
  const float* Wr = (const float*)d_in[1];
  const float* br = (const float*)d_in[2];
  const float* W1 = (const float*)d_in[3];
  const float* b1 = (const float*)d_in[4];
  const float* W2 = (const float*)d_in[5];
  const float* b2 = (const float*)d_in[6];
  float* out = (float*)d_out;

  char* ws = (char*)d_ws;
  size_t o = 0;
  auto take = [&](size_t bytes)->void*{
    void* p = ws + o; o += (bytes + 255) & ~(size_t)255; return p;
  };
  // mandatory
  unsigned short* W1T = (unsigned short*)take((size_t)NE*DM*DH*2);
  unsigned short* W2T = (unsigned short*)take((size_t)NE*DM*DH*2);
  int*   TOPI = (int*)take((size_t)NT_TOK*2*4);
  float* TOPW = (float*)take((size_t)NT_TOK*2*4);
  int*   ATOK = (int*)take((size_t)CAP*4);
  float* AWGT = (float*)take((size_t)CAP*4);
  int*   CNT  = (int*)take(256);     // counts[8] | cursor[8] | off[9]
  int* CUR = CNT + 8;
  int* OFF = CNT + 16;

  if (o + (size_t)BT*DH*2 > ws_size){
    fill_kernel<<<(unsigned)((out_size+255)/256), 256, 0, stream>>>(out, 4321.5f, (size_t)out_size);
    return;
  }

  // optional XB (f16 x)
  unsigned short* XB = nullptr;
  bool use_xb = false;
  {
    size_t xb_bytes = (size_t)NT_TOK*DM*2 + 256;
    size_t need_h  = (size_t)2048*DH*2;
    if (o + xb_bytes + need_h <= ws_size){
      use_xb = true;
      XB = (unsigned short*)take((size_t)NT_TOK*DM*2);
    }
  }
  // H chunk: as much as ws allows, up to CHUNK_ROWS
  size_t rem = ws_size - o;
  size_t cr = (rem / ((size_t)DH*2)) / BT * BT;
  if (cr > (size_t)CHUNK_ROWS) cr = CHUNK_ROWS;
  if (cr < BT){
    fill_kernel<<<(unsigned)((out_size+255)/256), 256, 0, stream>>>(out, 4321.5f, (size_t)out_size);
    return;
  }
  int CR = (int)cr;
  unsigned short* Hb = (unsigned short*)take((size_t)CR*DH*2);

  hipMemsetAsync(CNT, 0, 64, stream);
  hipMemsetAsync(ATOK, 0xFF, (size_t)CAP*4, stream);            // token = -1
  hipMemsetAsync(out, 0, (size_t)out_size*sizeof(float), stream);

  if (use_xb)
    cvt_f16_kernel<<<(NT_TOK*DM/8 + 255)/256, 256, 0, stream>>>(x, XB, NT_TOK*DM/8);
  transpose_f16_v2<<<dim3(DH/64, DM/64, NE), 256, 0, stream>>>(W1, W1T, DM, DH);
  transpose_f16_v2<<<dim3(DM/64, DH/64, NE), 256, 0, stream>>>(W2, W2T, DH, DM);
  router_kernel<<<NT_TOK/64, 256, 0, stream>>>(x, Wr, br, TOPI, TOPW, CNT);
  offsets_kernel<<<1, 1, 0, stream>>>(CNT, OFF);
  scatter_kernel<<<NT_TOK/256, 256, 0, stream>>>(TOPI, TOPW, OFF, CUR, ATOK, AWGT);

  for (int c0 = 0; c0 < CAP; c0 += CR){
    int rows = CAP - c0; if (rows > CR) rows = CR;
    int mtc = (rows + BM - 1)/BM;
    if (use_xb)
      gemm_big_kernel<DM, false><<<dim3((DH/BN)*mtc), 256, 0, stream>>>(
          XB, W1T, b1, ATOK, AWGT, OFF, Hb, out, c0, mtc);
    else
      gemm1_f32_kernel<<<dim3((DH/128)*((rows+127)/128)), 256, 0, stream>>>(
          x, W1T, b1, ATOK, OFF, Hb, c0);
    gemm_big_kernel<DH, true><<<dim3((DM/BN)*mtc), 256, 0, stream>>>(
        Hb, W2T, b2, ATOK, AWGT, OFF, Hb, out, c0, mtc);
  }
}

// Round 17
// 2185.664 us; speedup vs baseline: 1.0684x; 1.0684x over previous
//
#include <hip/hip_runtime.h>

#define NT_TOK 32768
#define DM 1024
#define DH 4096
#define NE 8
#define BT 256          /* segment padding quantum */
#define BM 128          /* tile M */
#define BN 128          /* tile N */
#define BK 32           /* K-tile (ring-3) */
#define CAP (NT_TOK*2 + NE*BT)   /* 67584 padded assignment capacity */
#define CHUNK_ROWS 32768

typedef _Float16 f16x8 __attribute__((ext_vector_type(8)));
typedef float f32x4 __attribute__((ext_vector_type(4)));
typedef float f32x8 __attribute__((ext_vector_type(8)));

__device__ __forceinline__ unsigned short f2h_bits(float v){
  _Float16 h = (_Float16)v;
  return __builtin_bit_cast(unsigned short, h);
}

__device__ __forceinline__ void async16(const void* g, void* l){
  __builtin_amdgcn_global_load_lds((const __attribute__((address_space(1))) void*)g,
                                   (__attribute__((address_space(3))) void*)l, 16, 0, 0);
}

// bijective XCD-aware remap (m204 variant)
__device__ __forceinline__ int xcd_remap(int orig, int nwg){
  int q = nwg >> 3, r = nwg & 7;
  int x = orig & 7, i = orig >> 3;
  int base = (x < r) ? x*(q+1) : r*(q+1) + (x-r)*q;
  return base + i;
}

// ---------------- prep kernels ----------------

__global__ __launch_bounds__(256) void cvt_f16_kernel(const float* __restrict__ src,
                                                      unsigned short* __restrict__ dst, int n8){
  int i = blockIdx.x*256 + threadIdx.x;
  if (i >= n8) return;
  float4 a = ((const float4*)src)[2*i];
  float4 b = ((const float4*)src)[2*i+1];
  union { unsigned short u[8]; uint4 v; } r;
  r.u[0]=f2h_bits(a.x); r.u[1]=f2h_bits(a.y); r.u[2]=f2h_bits(a.z); r.u[3]=f2h_bits(a.w);
  r.u[4]=f2h_bits(b.x); r.u[5]=f2h_bits(b.y); r.u[6]=f2h_bits(b.z); r.u[7]=f2h_bits(b.w);
  ((uint4*)dst)[i] = r.v;
}

// src [E][R][C] f32 -> dst [E][C][R] f16 ; 64x64 tiles, float4 reads, 8B f16 writes
__global__ __launch_bounds__(256) void transpose_f16_v2(const float* __restrict__ src,
    unsigned short* __restrict__ dst, int R, int C){
  __shared__ float t[64][65];
  int ez = blockIdx.z;
  const float* s = src + (size_t)ez*R*C;
  unsigned short* d = dst + (size_t)ez*R*C;
  int c0 = blockIdx.x*64, r0 = blockIdx.y*64;
  int tx = threadIdx.x & 15, ty = threadIdx.x >> 4;
  #pragma unroll
  for (int i=0;i<4;i++){
    float4 v = *(const float4*)&s[(size_t)(r0+ty+i*16)*C + c0 + tx*4];
    t[ty+i*16][tx*4+0]=v.x; t[ty+i*16][tx*4+1]=v.y;
    t[ty+i*16][tx*4+2]=v.z; t[ty+i*16][tx*4+3]=v.w;
  }
  __syncthreads();
  #pragma unroll
  for (int i=0;i<4;i++){
    int cc = ty + i*16;                       // src col -> dst row (c0+cc)
    union { unsigned short u[4]; uint2 v; } o;
    #pragma unroll
    for (int j=0;j<4;j++) o.u[j] = f2h_bits(t[tx*4+j][cc]);
    *(uint2*)&d[(size_t)(c0+cc)*R + r0 + tx*4] = o.v;
  }
}

// ---------------- router (f64 accumulate -> top-2 selection matches np ref) ----------------

__global__ __launch_bounds__(256) void router_kernel(const float* __restrict__ x,
    const float* __restrict__ Wr, const float* __restrict__ br,
    int* __restrict__ topi, float* __restrict__ topw, int* __restrict__ counts){
  __shared__ float wr_s[NE*DM];
  __shared__ int bcnt[NE];
  int tid = threadIdx.x;
  if (tid < NE) bcnt[tid] = 0;
  for (int idx=tid; idx<NE*DM; idx+=256){
    int k = idx>>3, e = idx&7;
    wr_s[e*DM + k] = Wr[idx];
  }
  __syncthreads();
  int w = tid>>6, lane = tid&63;
  for (int tt=0; tt<16; ++tt){
    int t = blockIdx.x*64 + w*16 + tt;
    const float* xr = x + (size_t)t*DM;
    double acc[NE];
    #pragma unroll
    for (int e=0;e<NE;e++) acc[e]=0.0;
    #pragma unroll
    for (int j=0;j<16;j++){
      float xv = xr[j*64 + lane];
      #pragma unroll
      for (int e=0;e<NE;e++) acc[e] += (double)xv * (double)wr_s[e*DM + j*64 + lane];
    }
    #pragma unroll
    for (int e=0;e<NE;e++){
      #pragma unroll
      for (int d=32; d; d>>=1) acc[e] += __shfl_xor(acc[e], d);
    }
    if (lane==0){
      double l[NE];
      #pragma unroll
      for (int e=0;e<NE;e++) l[e] = acc[e] + (double)br[e];
      int i0 = 0;
      #pragma unroll
      for (int e=1;e<NE;e++) if (l[e] > l[i0]) i0 = e;
      int i1 = (i0==0) ? 1 : 0;
      #pragma unroll
      for (int e=0;e<NE;e++) if (e != i0 && l[e] > l[i1]) i1 = e;
      double w0 = 1.0/(1.0 + exp(l[i1]-l[i0]));   // renormalized top-2 softmax, exact identity
      topi[2*t] = i0; topi[2*t+1] = i1;
      topw[2*t] = (float)w0; topw[2*t+1] = (float)(1.0-w0);
      atomicAdd(&bcnt[i0],1); atomicAdd(&bcnt[i1],1);   // LDS atomics
    }
  }
  __syncthreads();
  if (tid < NE && bcnt[tid] > 0) atomicAdd(&counts[tid], bcnt[tid]);
}

__global__ void offsets_kernel(const int* __restrict__ counts, int* __restrict__ off){
  if (threadIdx.x==0 && blockIdx.x==0){
    int o = 0;
    for (int e=0;e<NE;e++){ off[e] = o; o += ((counts[e]+BT-1)/BT)*BT; }
    off[NE] = o;
  }
}

// hierarchical scatter: LDS intra-block rank + one global atomic per expert per block
__global__ __launch_bounds__(256) void scatter_kernel(const int* __restrict__ topi,
    const float* __restrict__ topw, const int* __restrict__ off,
    int* __restrict__ cursor, int* __restrict__ atok, float* __restrict__ awgt){
  __shared__ int bcnt[NE];
  __shared__ int bbase[NE];
  int tid = threadIdx.x;
  if (tid < NE) bcnt[tid] = 0;
  __syncthreads();
  int t = blockIdx.x*256 + tid;
  int e0 = topi[2*t],   e1 = topi[2*t+1];
  int r0 = atomicAdd(&bcnt[e0], 1);
  int r1 = atomicAdd(&bcnt[e1], 1);
  __syncthreads();
  if (tid < NE) bbase[tid] = (bcnt[tid] > 0) ? atomicAdd(&cursor[tid], bcnt[tid]) : 0;
  __syncthreads();
  int s0 = off[e0] + bbase[e0] + r0;
  int s1 = off[e1] + bbase[e1] + r1;
  atok[s0] = t;  awgt[s0] = topw[2*t];
  atok[s1] = t;  awgt[s1] = topw[2*t+1];
}

// ---------------- 128x128 4-wave GEMM core (12 waves/CU, nt-fastest order) -----------------
// R16's occupancy config (3 blocks/CU x 4 waves = 12 waves/CU: 68 VGPR + 64 AGPR, 48KB
// ring-3 LDS) with R5-R14's PROVEN nt-fastest block order restored (R16's mt-fastest
// re-streamed the BIG operand A from HBM 8x: FETCH 205MB -> 1.11GB, HBM-bound at 28%).
// nt-fastest: consecutive blocks share the A panel (L2-hit); B small & cache-resident.
// Ring-3: tile t in buf[t%3]; stage t+2 during t (A phase 0, B phase 1; 4 instr/tile).
// Top-of-tile: outstanding {t,t+1} = 8 -> vmcnt(4) drains tile t (oldest-first, m135);
// tail vmcnt(0). buf(t+2)=buf(t-1), freed at t's top barrier.
// LDS slot map (R11-verified, 0 conflicts): slot(r,kc)=(r>>1)*8+((kc+4*(r&1))^((r>>1)&7))

template<int KDIM, bool IS_G2>
__global__ __launch_bounds__(256, 3) void gemm_big_kernel(
    const unsigned short* __restrict__ Asrc,    // XB (g1) or Hb (g2)
    const unsigned short* __restrict__ WT,      // W1T (g1) or W2T (g2), [E][N][K] f16
    const float* __restrict__ bias,             // b1 or b2
    const int* __restrict__ atok,
    const float* __restrict__ awgt,
    const int* __restrict__ offs,
    unsigned short* __restrict__ H,             // g1 out
    float* __restrict__ out,                    // g2 out
    int c0){
  __shared__ unsigned short As[3][BM*BK];       // 3 x 8 KB
  __shared__ unsigned short Bs[3][BN*BK];       // 3 x 8 KB
  const int NDIM = IS_G2 ? DM : DH;
  const int NT = NDIM/BN;
  int wg = xcd_remap(blockIdx.x, gridDim.x);
  int nt = wg % NT, mt = wg / NT;               // nt-fastest: consecutive wg share A panel
  int total = offs[NE];
  int m0 = c0 + mt*BM;
  if (m0 >= total) return;
  int e = 0;
  #pragma unroll
  for (int q=0;q<NE-1;q++) if (m0 >= offs[q+1]) e = q+1;
  int tid = threadIdx.x;
  int lane = tid&63, wid = tid>>6;
  int wm = wid>>1, wn = wid&1;                  // 2x2 waves; per-wave out 64x64

  // staging: slot c = j*256+tid (j<2) holds G[srow][schunk]:
  //   u=(c&7)^((c>>3)&7); srow=2*(c>>3)+(u>>2); schunk=u&3   (128 rows x 4 chunks)
  const unsigned short* agp[2];
  const unsigned short* bgp[2];
  int dofs[2];
  #pragma unroll
  for (int j=0;j<2;j++){
    int c = j*256 + tid;
    int u = (c&7) ^ ((c>>3)&7);
    int srow = ((c>>3)<<1) + (u>>2);
    int sch  = u&3;
    if (IS_G2){
      agp[j] = Asrc + (size_t)(m0 - c0 + srow)*KDIM + sch*8;
    } else {
      int tok = atok[m0 + srow];
      if (tok < 0) tok = 0;                 // pad rows: safe dummy gather
      agp[j] = Asrc + (size_t)tok*KDIM + sch*8;
    }
    bgp[j] = WT + ((size_t)e*NDIM + nt*BN + srow)*KDIM + sch*8;
    dofs[j] = c*8;                          // element offset of 16B slot c
  }

  // read offsets: elem = (r>>1)*64 + ((kc + 4*(r&1)) ^ ((r>>1)&7))*8 ; +512 per 16 rows
  int pos = (((lane>>4) + ((lane&1)<<2)) ^ ((lane>>1)&7)) << 3;
  int aoff0 = (wm*32 + ((lane&15)>>1))*64 + pos;
  int boff0 = (wn*32 + ((lane&15)>>1))*64 + pos;

  f32x4 acc[4][4];
  #pragma unroll
  for (int i=0;i<4;i++)
    #pragma unroll
    for (int j=0;j<4;j++) acc[i][j] = 0.0f;

  const int NKT = KDIM/BK;
  // prologue: prime tiles 0,1 (per tile A then B — matches in-loop order)
  #pragma unroll
  for (int t=0;t<2;t++){
    #pragma unroll
    for (int j=0;j<2;j++) async16(agp[j] + t*BK, &As[t][dofs[j]]);
    #pragma unroll
    for (int j=0;j<2;j++) async16(bgp[j] + t*BK, &Bs[t][dofs[j]]);
  }

  int cur = 0;
  for (int kt=0; kt<NKT; ++kt){
    if (kt < NKT-1) asm volatile("s_waitcnt vmcnt(4)" ::: "memory");
    else            asm volatile("s_waitcnt vmcnt(0)" ::: "memory");
    __builtin_amdgcn_s_barrier();
    int nxt2 = cur + 2; if (nxt2 >= 3) nxt2 -= 3;
    const unsigned short* Ab = &As[cur][0];
    const unsigned short* Bb = &Bs[cur][0];
    f16x8 b[4], a[4];
    #pragma unroll
    for (int nf=0;nf<4;nf++) b[nf] = *(const f16x8*)&Bb[boff0 + nf*512];
    #pragma unroll
    for (int mf=0;mf<4;mf++) a[mf] = *(const f16x8*)&Ab[aoff0 + mf*512];
    if (kt+2 < NKT){
      #pragma unroll
      for (int j=0;j<2;j++) async16(agp[j] + (size_t)(kt+2)*BK, &As[nxt2][dofs[j]]);
    }
    __builtin_amdgcn_s_setprio(1);
    #pragma unroll
    for (int mf=0;mf<4;mf++)
      #pragma unroll
      for (int nf=0;nf<2;nf++)
        acc[mf][nf] = __builtin_amdgcn_mfma_f32_16x16x32_f16(a[mf], b[nf], acc[mf][nf], 0,0,0);
    __builtin_amdgcn_s_setprio(0);
    __builtin_amdgcn_s_barrier();           // mid-tile (R7/R8-measured win)
    if (kt+2 < NKT){
      #pragma unroll
      for (int j=0;j<2;j++) async16(bgp[j] + (size_t)(kt+2)*BK, &Bs[nxt2][dofs[j]]);
    }
    __builtin_amdgcn_s_setprio(1);
    #pragma unroll
    for (int mf=0;mf<4;mf++)
      #pragma unroll
      for (int nf=2;nf<4;nf++)
        acc[mf][nf] = __builtin_amdgcn_mfma_f32_16x16x32_f16(a[mf], b[nf], acc[mf][nf], 0,0,0);
    __builtin_amdgcn_s_setprio(0);
    cur = (cur + 1 == 3) ? 0 : cur + 1;
  }

  // epilogue (verified C mapping)
  int nbase = nt*BN + wn*64 + (lane&15);
  if (!IS_G2){
    const float* be = bias + (size_t)e*DH;
    int rloc = (m0 - c0) + wm*64 + ((lane>>4)<<2);
    #pragma unroll
    for (int mf=0;mf<4;mf++)
      #pragma unroll
      for (int nf=0;nf<4;nf++){
        int nn = nbase + nf*16;
        float bv = be[nn];
        #pragma unroll
        for (int r2=0;r2<4;r2++){
          float v = acc[mf][nf][r2] + bv;
          float g = 0.5f*v*(1.0f + erff(v*0.70710678118654752f));
          H[(size_t)(rloc + mf*16 + r2)*DH + nn] = f2h_bits(g);
        }
      }
  } else {
    const float* be = bias + (size_t)e*DM;
    int sbase = m0 + wm*64 + ((lane>>4)<<2);
    #pragma unroll
    for (int mf=0;mf<4;mf++){
      #pragma unroll
      for (int r2=0;r2<4;r2++){
        int slot = sbase + mf*16 + r2;
        int tok = atok[slot];
        float wgt = awgt[slot];
        if (tok >= 0){
          #pragma unroll
          for (int nf=0;nf<4;nf++){
            int nn = nbase + nf*16;
            float v = acc[mf][nf][r2] + be[nn];
            atomicAdd(&out[(size_t)tok*DM + nn], wgt*v);
          }
        }
      }
    }
  }
}

// ---------------- GEMM1 fallback (A staged from f32 x, no XB; 128x128 tile) ----------------

__global__ __launch_bounds__(256) void gemm1_f32_kernel(
    const float* __restrict__ xf, const unsigned short* __restrict__ W1T,
    const float* __restrict__ b1, const int* __restrict__ atok,
    const int* __restrict__ offs, unsigned short* __restrict__ H, int c0){
  __shared__ float Asf[128*64];
  __shared__ unsigned short Bsld[128*64];
  const int NT = DH/128;
  int wg = xcd_remap(blockIdx.x, gridDim.x);
  int nt = wg % NT, mt = wg / NT;
  int total = offs[NE];
  int m0 = c0 + mt*128;
  if (m0 >= total) return;
  int e = 0;
  #pragma unroll
  for (int q=0;q<NE-1;q++) if (m0 >= offs[q+1]) e = q+1;
  int tid = threadIdx.x;
  const void* ag[8];
  int aofs[8];
  #pragma unroll
  for (int j=0;j<8;j++){
    int c = j*256 + tid;
    int r = c>>4, sb = (c&15)*16;
    int tok = atok[m0 + r];
    if (tok < 0) tok = 0;
    ag[j] = (const void*)((const char*)(xf + (size_t)tok*DM) + sb);
    aofs[j] = c*16;
  }
  const unsigned short* bg[4];
  int bofs[4];
  #pragma unroll
  for (int j=0;j<4;j++){
    int c = j*256 + tid;
    int r = c>>3, s = c&7;
    bg[j] = W1T + ((size_t)e*DH + nt*128 + r)*DM + s*8;
    bofs[j] = c*16;
  }
  f32x4 acc[4][4];
  #pragma unroll
  for (int i=0;i<4;i++)
    #pragma unroll
    for (int j=0;j<4;j++) acc[i][j] = 0.0f;
  int lane = tid&63;
  int wm = tid>>7, wn = (tid>>6)&1;
  int arow = wm*64 + (lane&15);
  int ak0  = (lane>>4)*8;
  int brr  = (wn*64 + (lane&15))*64 + ak0;
  for (int kt=0; kt<DM/64; ++kt){
    #pragma unroll
    for (int j=0;j<8;j++)
      async16((const char*)ag[j] + (size_t)kt*64*4, (char*)Asf + aofs[j]);
    #pragma unroll
    for (int j=0;j<4;j++)
      async16(bg[j] + (size_t)kt*64, (char*)Bsld + bofs[j]);
    __syncthreads();
    #pragma unroll
    for (int kk=0; kk<64; kk+=32){
      f16x8 a[4], b[4];
      #pragma unroll
      for (int f=0;f<4;f++){
        f32x8 v = *(const f32x8*)&Asf[(arow + f*16)*64 + ak0 + kk];
        a[f] = __builtin_convertvector(v, f16x8);
        b[f] = *(const f16x8*)&Bsld[brr + f*16*64 + kk];
      }
      #pragma unroll
      for (int i=0;i<4;i++)
        #pragma unroll
        for (int j2=0;j2<4;j2++)
          acc[i][j2] = __builtin_amdgcn_mfma_f32_16x16x32_f16(a[i], b[j2], acc[i][j2], 0,0,0);
    }
    __syncthreads();
  }
  const float* b1e = b1 + (size_t)e*DH;
  int rloc = (m0 - c0) + wm*64 + ((lane>>4)<<2);
  int nbase = nt*128 + wn*64 + (lane&15);
  #pragma unroll
  for (int i=0;i<4;i++)
    #pragma unroll
    for (int j=0;j<4;j++){
      int nn = nbase + j*16;
      float bv = b1e[nn];
      #pragma unroll
      for (int r2=0;r2<4;r2++){
        float v = acc[i][j][r2] + bv;
        float g = 0.5f*v*(1.0f + erff(v*0.70710678118654752f));
        H[(size_t)(rloc + i*16 + r2)*DH + nn] = f2h_bits(g);
      }
    }
}

__global__ void fill_kernel(float* p, float v, size_t n){
  size_t i = (size_t)blockIdx.x*256 + threadIdx.x;
  if (i < n) p[i] = v;
}

// ---------------- launch ----------------

extern "C" void kernel_launch(void* const* d_in, const int* in_sizes, int n_in,
                              void* d_out, int out_size, void* d_ws, size_t ws_size,
                              hipStream_t stream){
  const float* x  = (const float*)d_in[0];
  const float* Wr = (const float*)d_in[1];
  const float* br = (const float*)d_in[2];
  const float* W1 = (const float*)d_in[3];
  const float* b1 = (const float*)d_in[4];
  const float* W2 = (const float*)d_in[5];
  const float* b2 = (const float*)d_in[6];
  float* out = (float*)d_out;

  char* ws = (char*)d_ws;
  size_t o = 0;
  auto take = [&](size_t bytes)->void*{
    void* p = ws + o; o += (bytes + 255) & ~(size_t)255; return p;
  };
  // mandatory
  unsigned short* W1T = (unsigned short*)take((size_t)NE*DM*DH*2);
  unsigned short* W2T = (unsigned short*)take((size_t)NE*DM*DH*2);
  int*   TOPI = (int*)take((size_t)NT_TOK*2*4);
  float* TOPW = (float*)take((size_t)NT_TOK*2*4);
  int*   ATOK = (int*)take((size_t)CAP*4);
  float* AWGT = (float*)take((size_t)CAP*4);
  int*   CNT  = (int*)take(256);     // counts[8] | cursor[8] | off[9]
  int* CUR = CNT + 8;
  int* OFF = CNT + 16;

  if (o + (size_t)BT*DH*2 > ws_size){
    fill_kernel<<<(unsigned)((out_size+255)/256), 256, 0, stream>>>(out, 4321.5f, (size_t)out_size);
    return;
  }

  // optional XB (f16 x)
  unsigned short* XB = nullptr;
  bool use_xb = false;
  {
    size_t xb_bytes = (size_t)NT_TOK*DM*2 + 256;
    size_t need_h  = (size_t)2048*DH*2;
    if (o + xb_bytes + need_h <= ws_size){
      use_xb = true;
      XB = (unsigned short*)take((size_t)NT_TOK*DM*2);
    }
  }
  // H chunk: as much as ws allows, up to CHUNK_ROWS
  size_t rem = ws_size - o;
  size_t cr = (rem / ((size_t)DH*2)) / BT * BT;
  if (cr > (size_t)CHUNK_ROWS) cr = CHUNK_ROWS;
  if (cr < BT){
    fill_kernel<<<(unsigned)((out_size+255)/256), 256, 0, stream>>>(out, 4321.5f, (size_t)out_size);
    return;
  }
  int CR = (int)cr;
  unsigned short* Hb = (unsigned short*)take((size_t)CR*DH*2);

  hipMemsetAsync(CNT, 0, 64, stream);
  hipMemsetAsync(ATOK, 0xFF, (size_t)CAP*4, stream);            // token = -1
  hipMemsetAsync(out, 0, (size_t)out_size*sizeof(float), stream);

  if (use_xb)
    cvt_f16_kernel<<<(NT_TOK*DM/8 + 255)/256, 256, 0, stream>>>(x, XB, NT_TOK*DM/8);
  transpose_f16_v2<<<dim3(DH/64, DM/64, NE), 256, 0, stream>>>(W1, W1T, DM, DH);
  transpose_f16_v2<<<dim3(DM/64, DH/64, NE), 256, 0, stream>>>(W2, W2T, DH, DM);
  router_kernel<<<NT_TOK/64, 256, 0, stream>>>(x, Wr, br, TOPI, TOPW, CNT);
  offsets_kernel<<<1, 1, 0, stream>>>(CNT, OFF);
  scatter_kernel<<<NT_TOK/256, 256, 0, stream>>>(TOPI, TOPW, OFF, CUR, ATOK, AWGT);

  for (int c0 = 0; c0 < CAP; c0 += CR){
    int rows = CAP - c0; if (rows > CR) rows = CR;
    int mtc = (rows + BM - 1)/BM;
    if (use_xb)
      gemm_big_kernel<DM, false><<<dim3((DH/BN)*mtc), 256, 0, stream>>>(
          XB, W1T, b1, ATOK, AWGT, OFF, Hb, out, c0);
    else
      gemm1_f32_kernel<<<dim3((DH/128)*((rows+127)/128)), 256, 0, stream>>>(
          x, W1T, b1, ATOK, OFF, Hb, c0);
    gemm_big_kernel<DH, true><<<dim3((DM/BN)*mtc), 256, 0, stream>>>(
        Hb, W2T, b2, ATOK, AWGT, OFF, Hb, out, c0);
  }
}

// Round 18
// 2097.504 us; speedup vs baseline: 1.1133x; 1.0420x over previous
//
#include <hip/hip_runtime.h>

#define NT_TOK 32768
#define DM 1024
#define DH 4096
#define NE 8
#define BT 256          /* segment padding quantum */
#define BM 128          /* tile M */
#define BN 128          /* tile N */
#define BK 32           /* K-tile (ring-3) */
#define CAP (NT_TOK*2 + NE*BT)   /* 67584 padded assignment capacity */
#define CHUNK_ROWS 33792         /* = CAP/2: two balanced chunks, no tail */

typedef _Float16 f16x8 __attribute__((ext_vector_type(8)));
typedef float f32x4 __attribute__((ext_vector_type(4)));
typedef float f32x8 __attribute__((ext_vector_type(8)));

__device__ __forceinline__ unsigned short f2h_bits(float v){
  _Float16 h = (_Float16)v;
  return __builtin_bit_cast(unsigned short, h);
}

__device__ __forceinline__ void async16(const void* g, void* l){
  __builtin_amdgcn_global_load_lds((const __attribute__((address_space(1))) void*)g,
                                   (__attribute__((address_space(3))) void*)l, 16, 0, 0);
}

// bijective XCD-aware remap (m204 variant)
__device__ __forceinline__ int xcd_remap(int orig, int nwg){
  int q = nwg >> 3, r = nwg & 7;
  int x = orig & 7, i = orig >> 3;
  int base = (x < r) ? x*(q+1) : r*(q+1) + (x-r)*q;
  return base + i;
}

// ---------------- prep kernels ----------------

__global__ __launch_bounds__(256) void cvt_f16_kernel(const float* __restrict__ src,
                                                      unsigned short* __restrict__ dst, int n8){
  int i = blockIdx.x*256 + threadIdx.x;
  if (i >= n8) return;
  float4 a = ((const float4*)src)[2*i];
  float4 b = ((const float4*)src)[2*i+1];
  union { unsigned short u[8]; uint4 v; } r;
  r.u[0]=f2h_bits(a.x); r.u[1]=f2h_bits(a.y); r.u[2]=f2h_bits(a.z); r.u[3]=f2h_bits(a.w);
  r.u[4]=f2h_bits(b.x); r.u[5]=f2h_bits(b.y); r.u[6]=f2h_bits(b.z); r.u[7]=f2h_bits(b.w);
  ((uint4*)dst)[i] = r.v;
}

// src [E][R][C] f32 -> dst [E][C][R] f16 ; 64x64 tiles, float4 reads, 8B f16 writes
__global__ __launch_bounds__(256) void transpose_f16_v2(const float* __restrict__ src,
    unsigned short* __restrict__ dst, int R, int C){
  __shared__ float t[64][65];
  int ez = blockIdx.z;
  const float* s = src + (size_t)ez*R*C;
  unsigned short* d = dst + (size_t)ez*R*C;
  int c0 = blockIdx.x*64, r0 = blockIdx.y*64;
  int tx = threadIdx.x & 15, ty = threadIdx.x >> 4;
  #pragma unroll
  for (int i=0;i<4;i++){
    float4 v = *(const float4*)&s[(size_t)(r0+ty+i*16)*C + c0 + tx*4];
    t[ty+i*16][tx*4+0]=v.x; t[ty+i*16][tx*4+1]=v.y;
    t[ty+i*16][tx*4+2]=v.z; t[ty+i*16][tx*4+3]=v.w;
  }
  __syncthreads();
  #pragma unroll
  for (int i=0;i<4;i++){
    int cc = ty + i*16;                       // src col -> dst row (c0+cc)
    union { unsigned short u[4]; uint2 v; } o;
    #pragma unroll
    for (int j=0;j<4;j++) o.u[j] = f2h_bits(t[tx*4+j][cc]);
    *(uint2*)&d[(size_t)(c0+cc)*R + r0 + tx*4] = o.v;
  }
}

// ---------------- router (f64 accumulate -> top-2 selection matches np ref) ----------------

__global__ __launch_bounds__(256) void router_kernel(const float* __restrict__ x,
    const float* __restrict__ Wr, const float* __restrict__ br,
    int* __restrict__ topi, float* __restrict__ topw, int* __restrict__ counts){
  __shared__ float wr_s[NE*DM];
  __shared__ int bcnt[NE];
  int tid = threadIdx.x;
  if (tid < NE) bcnt[tid] = 0;
  for (int idx=tid; idx<NE*DM; idx+=256){
    int k = idx>>3, e = idx&7;
    wr_s[e*DM + k] = Wr[idx];
  }
  __syncthreads();
  int w = tid>>6, lane = tid&63;
  for (int tt=0; tt<16; ++tt){
    int t = blockIdx.x*64 + w*16 + tt;
    const float* xr = x + (size_t)t*DM;
    double acc[NE];
    #pragma unroll
    for (int e=0;e<NE;e++) acc[e]=0.0;
    #pragma unroll
    for (int j=0;j<16;j++){
      float xv = xr[j*64 + lane];
      #pragma unroll
      for (int e=0;e<NE;e++) acc[e] += (double)xv * (double)wr_s[e*DM + j*64 + lane];
    }
    #pragma unroll
    for (int e=0;e<NE;e++){
      #pragma unroll
      for (int d=32; d; d>>=1) acc[e] += __shfl_xor(acc[e], d);
    }
    if (lane==0){
      double l[NE];
      #pragma unroll
      for (int e=0;e<NE;e++) l[e] = acc[e] + (double)br[e];
      int i0 = 0;
      #pragma unroll
      for (int e=1;e<NE;e++) if (l[e] > l[i0]) i0 = e;
      int i1 = (i0==0) ? 1 : 0;
      #pragma unroll
      for (int e=0;e<NE;e++) if (e != i0 && l[e] > l[i1]) i1 = e;
      double w0 = 1.0/(1.0 + exp(l[i1]-l[i0]));   // renormalized top-2 softmax, exact identity
      topi[2*t] = i0; topi[2*t+1] = i1;
      topw[2*t] = (float)w0; topw[2*t+1] = (float)(1.0-w0);
      atomicAdd(&bcnt[i0],1); atomicAdd(&bcnt[i1],1);   // LDS atomics
    }
  }
  __syncthreads();
  if (tid < NE && bcnt[tid] > 0) atomicAdd(&counts[tid], bcnt[tid]);
}

__global__ void offsets_kernel(const int* __restrict__ counts, int* __restrict__ off){
  if (threadIdx.x==0 && blockIdx.x==0){
    int o = 0;
    for (int e=0;e<NE;e++){ off[e] = o; o += ((counts[e]+BT-1)/BT)*BT; }
    off[NE] = o;
  }
}

// hierarchical scatter: LDS intra-block rank + one global atomic per expert per block
__global__ __launch_bounds__(256) void scatter_kernel(const int* __restrict__ topi,
    const float* __restrict__ topw, const int* __restrict__ off,
    int* __restrict__ cursor, int* __restrict__ atok, float* __restrict__ awgt){
  __shared__ int bcnt[NE];
  __shared__ int bbase[NE];
  int tid = threadIdx.x;
  if (tid < NE) bcnt[tid] = 0;
  __syncthreads();
  int t = blockIdx.x*256 + tid;
  int e0 = topi[2*t],   e1 = topi[2*t+1];
  int r0 = atomicAdd(&bcnt[e0], 1);
  int r1 = atomicAdd(&bcnt[e1], 1);
  __syncthreads();
  if (tid < NE) bbase[tid] = (bcnt[tid] > 0) ? atomicAdd(&cursor[tid], bcnt[tid]) : 0;
  __syncthreads();
  int s0 = off[e0] + bbase[e0] + r0;
  int s1 = off[e1] + bbase[e1] + r1;
  atok[s0] = t;  awgt[s0] = topw[2*t];
  atok[s1] = t;  awgt[s1] = topw[2*t+1];
}

// ---------------- 128x128 4-wave GEMM core (12 waves/CU, nt-fastest) — R17 best ------------
// 3 blocks/CU x 4 waves = 12 waves/CU (68 VGPR + 64 AGPR, 48KB ring-3 LDS); nt-fastest
// block order (consecutive wg share the BIG operand A panel -> L2-hit; B cache-resident).
// Ring-3: tile t in buf[t%3]; stage t+2 during t (A phase 0, B phase 1; 4 instr/tile).
// Top-of-tile: outstanding {t,t+1} = 8 -> vmcnt(4) drains tile t (oldest-first, m135);
// tail vmcnt(0). buf(t+2)=buf(t-1), freed at t's top barrier.
// LDS slot map (R11-verified, 0 conflicts): slot(r,kc)=(r>>1)*8+((kc+4*(r&1))^((r>>1)&7))

template<int KDIM, bool IS_G2>
__global__ __launch_bounds__(256, 3) void gemm_big_kernel(
    const unsigned short* __restrict__ Asrc,    // XB (g1) or Hb (g2)
    const unsigned short* __restrict__ WT,      // W1T (g1) or W2T (g2), [E][N][K] f16
    const float* __restrict__ bias,             // b1 or b2
    const int* __restrict__ atok,
    const float* __restrict__ awgt,
    const int* __restrict__ offs,
    unsigned short* __restrict__ H,             // g1 out
    float* __restrict__ out,                    // g2 out
    int c0){
  __shared__ unsigned short As[3][BM*BK];       // 3 x 8 KB
  __shared__ unsigned short Bs[3][BN*BK];       // 3 x 8 KB
  const int NDIM = IS_G2 ? DM : DH;
  const int NT = NDIM/BN;
  int wg = xcd_remap(blockIdx.x, gridDim.x);
  int nt = wg % NT, mt = wg / NT;               // nt-fastest: consecutive wg share A panel
  int total = offs[NE];
  int m0 = c0 + mt*BM;
  if (m0 >= total) return;
  int e = 0;
  #pragma unroll
  for (int q=0;q<NE-1;q++) if (m0 >= offs[q+1]) e = q+1;
  int tid = threadIdx.x;
  int lane = tid&63, wid = tid>>6;
  int wm = wid>>1, wn = wid&1;                  // 2x2 waves; per-wave out 64x64

  // staging: slot c = j*256+tid (j<2) holds G[srow][schunk]:
  //   u=(c&7)^((c>>3)&7); srow=2*(c>>3)+(u>>2); schunk=u&3   (128 rows x 4 chunks)
  const unsigned short* agp[2];
  const unsigned short* bgp[2];
  int dofs[2];
  #pragma unroll
  for (int j=0;j<2;j++){
    int c = j*256 + tid;
    int u = (c&7) ^ ((c>>3)&7);
    int srow = ((c>>3)<<1) + (u>>2);
    int sch  = u&3;
    if (IS_G2){
      agp[j] = Asrc + (size_t)(m0 - c0 + srow)*KDIM + sch*8;
    } else {
      int tok = atok[m0 + srow];
      if (tok < 0) tok = 0;                 // pad rows: safe dummy gather
      agp[j] = Asrc + (size_t)tok*KDIM + sch*8;
    }
    bgp[j] = WT + ((size_t)e*NDIM + nt*BN + srow)*KDIM + sch*8;
    dofs[j] = c*8;                          // element offset of 16B slot c
  }

  // read offsets: elem = (r>>1)*64 + ((kc + 4*(r&1)) ^ ((r>>1)&7))*8 ; +512 per 16 rows
  int pos = (((lane>>4) + ((lane&1)<<2)) ^ ((lane>>1)&7)) << 3;
  int aoff0 = (wm*32 + ((lane&15)>>1))*64 + pos;
  int boff0 = (wn*32 + ((lane&15)>>1))*64 + pos;

  f32x4 acc[4][4];
  #pragma unroll
  for (int i=0;i<4;i++)
    #pragma unroll
    for (int j=0;j<4;j++) acc[i][j] = 0.0f;

  const int NKT = KDIM/BK;
  // prologue: prime tiles 0,1 (per tile A then B — matches in-loop order)
  #pragma unroll
  for (int t=0;t<2;t++){
    #pragma unroll
    for (int j=0;j<2;j++) async16(agp[j] + t*BK, &As[t][dofs[j]]);
    #pragma unroll
    for (int j=0;j<2;j++) async16(bgp[j] + t*BK, &Bs[t][dofs[j]]);
  }

  int cur = 0;
  for (int kt=0; kt<NKT; ++kt){
    if (kt < NKT-1) asm volatile("s_waitcnt vmcnt(4)" ::: "memory");
    else            asm volatile("s_waitcnt vmcnt(0)" ::: "memory");
    __builtin_amdgcn_s_barrier();
    int nxt2 = cur + 2; if (nxt2 >= 3) nxt2 -= 3;
    const unsigned short* Ab = &As[cur][0];
    const unsigned short* Bb = &Bs[cur][0];
    f16x8 b[4], a[4];
    #pragma unroll
    for (int nf=0;nf<4;nf++) b[nf] = *(const f16x8*)&Bb[boff0 + nf*512];
    #pragma unroll
    for (int mf=0;mf<4;mf++) a[mf] = *(const f16x8*)&Ab[aoff0 + mf*512];
    if (kt+2 < NKT){
      #pragma unroll
      for (int j=0;j<2;j++) async16(agp[j] + (size_t)(kt+2)*BK, &As[nxt2][dofs[j]]);
    }
    __builtin_amdgcn_s_setprio(1);
    #pragma unroll
    for (int mf=0;mf<4;mf++)
      #pragma unroll
      for (int nf=0;nf<2;nf++)
        acc[mf][nf] = __builtin_amdgcn_mfma_f32_16x16x32_f16(a[mf], b[nf], acc[mf][nf], 0,0,0);
    __builtin_amdgcn_s_setprio(0);
    __builtin_amdgcn_s_barrier();           // mid-tile (R7/R8-measured win)
    if (kt+2 < NKT){
      #pragma unroll
      for (int j=0;j<2;j++) async16(bgp[j] + (size_t)(kt+2)*BK, &Bs[nxt2][dofs[j]]);
    }
    __builtin_amdgcn_s_setprio(1);
    #pragma unroll
    for (int mf=0;mf<4;mf++)
      #pragma unroll
      for (int nf=2;nf<4;nf++)
        acc[mf][nf] = __builtin_amdgcn_mfma_f32_16x16x32_f16(a[mf], b[nf], acc[mf][nf], 0,0,0);
    __builtin_amdgcn_s_setprio(0);
    cur = (cur + 1 == 3) ? 0 : cur + 1;
  }

  // epilogue (verified C mapping)
  int nbase = nt*BN + wn*64 + (lane&15);
  if (!IS_G2){
    const float* be = bias + (size_t)e*DH;
    int rloc = (m0 - c0) + wm*64 + ((lane>>4)<<2);
    #pragma unroll
    for (int mf=0;mf<4;mf++)
      #pragma unroll
      for (int nf=0;nf<4;nf++){
        int nn = nbase + nf*16;
        float bv = be[nn];
        #pragma unroll
        for (int r2=0;r2<4;r2++){
          float v = acc[mf][nf][r2] + bv;
          float g = 0.5f*v*(1.0f + erff(v*0.70710678118654752f));
          H[(size_t)(rloc + mf*16 + r2)*DH + nn] = f2h_bits(g);
        }
      }
  } else {
    const float* be = bias + (size_t)e*DM;
    int sbase = m0 + wm*64 + ((lane>>4)<<2);
    #pragma unroll
    for (int mf=0;mf<4;mf++){
      #pragma unroll
      for (int r2=0;r2<4;r2++){
        int slot = sbase + mf*16 + r2;
        int tok = atok[slot];
        float wgt = awgt[slot];
        if (tok >= 0){
          #pragma unroll
          for (int nf=0;nf<4;nf++){
            int nn = nbase + nf*16;
            float v = acc[mf][nf][r2] + be[nn];
            atomicAdd(&out[(size_t)tok*DM + nn], wgt*v);
          }
        }
      }
    }
  }
}

// ---------------- GEMM1 fallback (A staged from f32 x, no XB; 128x128 tile) ----------------

__global__ __launch_bounds__(256) void gemm1_f32_kernel(
    const float* __restrict__ xf, const unsigned short* __restrict__ W1T,
    const float* __restrict__ b1, const int* __restrict__ atok,
    const int* __restrict__ offs, unsigned short* __restrict__ H, int c0){
  __shared__ float Asf[128*64];
  __shared__ unsigned short Bsld[128*64];
  const int NT = DH/128;
  int wg = xcd_remap(blockIdx.x, gridDim.x);
  int nt = wg % NT, mt = wg / NT;
  int total = offs[NE];
  int m0 = c0 + mt*128;
  if (m0 >= total) return;
  int e = 0;
  #pragma unroll
  for (int q=0;q<NE-1;q++) if (m0 >= offs[q+1]) e = q+1;
  int tid = threadIdx.x;
  const void* ag[8];
  int aofs[8];
  #pragma unroll
  for (int j=0;j<8;j++){
    int c = j*256 + tid;
    int r = c>>4, sb = (c&15)*16;
    int tok = atok[m0 + r];
    if (tok < 0) tok = 0;
    ag[j] = (const void*)((const char*)(xf + (size_t)tok*DM) + sb);
    aofs[j] = c*16;
  }
  const unsigned short* bg[4];
  int bofs[4];
  #pragma unroll
  for (int j=0;j<4;j++){
    int c = j*256 + tid;
    int r = c>>3, s = c&7;
    bg[j] = W1T + ((size_t)e*DH + nt*128 + r)*DM + s*8;
    bofs[j] = c*16;
  }
  f32x4 acc[4][4];
  #pragma unroll
  for (int i=0;i<4;i++)
    #pragma unroll
    for (int j=0;j<4;j++) acc[i][j] = 0.0f;
  int lane = tid&63;
  int wm = tid>>7, wn = (tid>>6)&1;
  int arow = wm*64 + (lane&15);
  int ak0  = (lane>>4)*8;
  int brr  = (wn*64 + (lane&15))*64 + ak0;
  for (int kt=0; kt<DM/64; ++kt){
    #pragma unroll
    for (int j=0;j<8;j++)
      async16((const char*)ag[j] + (size_t)kt*64*4, (char*)Asf + aofs[j]);
    #pragma unroll
    for (int j=0;j<4;j++)
      async16(bg[j] + (size_t)kt*64, (char*)Bsld + bofs[j]);
    __syncthreads();
    #pragma unroll
    for (int kk=0; kk<64; kk+=32){
      f16x8 a[4], b[4];
      #pragma unroll
      for (int f=0;f<4;f++){
        f32x8 v = *(const f32x8*)&Asf[(arow + f*16)*64 + ak0 + kk];
        a[f] = __builtin_convertvector(v, f16x8);
        b[f] = *(const f16x8*)&Bsld[brr + f*16*64 + kk];
      }
      #pragma unroll
      for (int i=0;i<4;i++)
        #pragma unroll
        for (int j2=0;j2<4;j2++)
          acc[i][j2] = __builtin_amdgcn_mfma_f32_16x16x32_f16(a[i], b[j2], acc[i][j2], 0,0,0);
    }
    __syncthreads();
  }
  const float* b1e = b1 + (size_t)e*DH;
  int rloc = (m0 - c0) + wm*64 + ((lane>>4)<<2);
  int nbase = nt*128 + wn*64 + (lane&15);
  #pragma unroll
  for (int i=0;i<4;i++)
    #pragma unroll
    for (int j=0;j<4;j++){
      int nn = nbase + j*16;
      float bv = b1e[nn];
      #pragma unroll
      for (int r2=0;r2<4;r2++){
        float v = acc[i][j][r2] + bv;
        float g = 0.5f*v*(1.0f + erff(v*0.70710678118654752f));
        H[(size_t)(rloc + i*16 + r2)*DH + nn] = f2h_bits(g);
      }
    }
}

__global__ void fill_kernel(float* p, float v, size_t n){
  size_t i = (size_t)blockIdx.x*256 + threadIdx.x;
  if (i < n) p[i] = v;
}

// ---------------- launch ----------------

extern "C" void kernel_launch(void* const* d_in, const int* in_sizes, int n_in,
                              void* d_out, int out_size, void* d_ws, size_t ws_size,
                              hipStream_t stream){
  const float* x  = (const float*)d_in[0];
  const float* Wr = (const float*)d_in[1];
  const float* br = (const float*)d_in[2];
  const float* W1 = (const float*)d_in[3];
  const float* b1 = (const float*)d_in[4];
  const float* W2 = (const float*)d_in[5];
  const float* b2 = (const float*)d_in[6];
  float* out = (float*)d_out;

  char* ws = (char*)d_ws;
  size_t o = 0;
  auto take = [&](size_t bytes)->void*{
    void* p = ws + o; o += (bytes + 255) & ~(size_t)255; return p;
  };
  // mandatory
  unsigned short* W1T = (unsigned short*)take((size_t)NE*DM*DH*2);
  unsigned short* W2T = (unsigned short*)take((size_t)NE*DM*DH*2);
  int*   TOPI = (int*)take((size_t)NT_TOK*2*4);
  float* TOPW = (float*)take((size_t)NT_TOK*2*4);
  int*   ATOK = (int*)take((size_t)CAP*4);
  float* AWGT = (float*)take((size_t)CAP*4);
  int*   CNT  = (int*)take(256);     // counts[8] | cursor[8] | off[9]
  int* CUR = CNT + 8;
  int* OFF = CNT + 16;

  if (o + (size_t)BT*DH*2 > ws_size){
    fill_kernel<<<(unsigned)((out_size+255)/256), 256, 0, stream>>>(out, 4321.5f, (size_t)out_size);
    return;
  }

  // optional XB (f16 x)
  unsigned short* XB = nullptr;
  bool use_xb = false;
  {
    size_t xb_bytes = (size_t)NT_TOK*DM*2 + 256;
    size_t need_h  = (size_t)2048*DH*2;
    if (o + xb_bytes + need_h <= ws_size){
      use_xb = true;
      XB = (unsigned short*)take((size_t)NT_TOK*DM*2);
    }
  }
  // H chunk: as much as ws allows, up to CHUNK_ROWS (= CAP/2 -> 2 balanced chunks)
  size_t rem = ws_size - o;
  size_t cr = (rem / ((size_t)DH*2)) / BT * BT;
  if (cr > (size_t)CHUNK_ROWS) cr = CHUNK_ROWS;
  if (cr < BT){
    fill_kernel<<<(unsigned)((out_size+255)/256), 256, 0, stream>>>(out, 4321.5f, (size_t)out_size);
    return;
  }
  int CR = (int)cr;
  unsigned short* Hb = (unsigned short*)take((size_t)CR*DH*2);

  hipMemsetAsync(CNT, 0, 64, stream);
  hipMemsetAsync(ATOK, 0xFF, (size_t)CAP*4, stream);            // token = -1
  hipMemsetAsync(out, 0, (size_t)out_size*sizeof(float), stream);

  if (use_xb)
    cvt_f16_kernel<<<(NT_TOK*DM/8 + 255)/256, 256, 0, stream>>>(x, XB, NT_TOK*DM/8);
  transpose_f16_v2<<<dim3(DH/64, DM/64, NE), 256, 0, stream>>>(W1, W1T, DM, DH);
  transpose_f16_v2<<<dim3(DM/64, DH/64, NE), 256, 0, stream>>>(W2, W2T, DH, DM);
  router_kernel<<<NT_TOK/64, 256, 0, stream>>>(x, Wr, br, TOPI, TOPW, CNT);
  offsets_kernel<<<1, 1, 0, stream>>>(CNT, OFF);
  scatter_kernel<<<NT_TOK/256, 256, 0, stream>>>(TOPI, TOPW, OFF, CUR, ATOK, AWGT);

  for (int c0 = 0; c0 < CAP; c0 += CR){
    int rows = CAP - c0; if (rows > CR) rows = CR;
    int mtc = (rows + BM - 1)/BM;
    if (use_xb)
      gemm_big_kernel<DM, false><<<dim3((DH/BN)*mtc), 256, 0, stream>>>(
          XB, W1T, b1, ATOK, AWGT, OFF, Hb, out, c0);
    else
      gemm1_f32_kernel<<<dim3((DH/128)*((rows+127)/128)), 256, 0, stream>>>(
          x, W1T, b1, ATOK, OFF, Hb, c0);
    gemm_big_kernel<DH, true><<<dim3((DM/BN)*mtc), 256, 0, stream>>>(
        Hb, W2T, b2, ATOK, AWGT, OFF, Hb, out, c0);
  }
}

// Round 19
// 2076.072 us; speedup vs baseline: 1.1248x; 1.0103x over previous
//
#include <hip/hip_runtime.h>

#define NT_TOK 32768
#define DM 1024
#define DH 4096
#define NE 8
#define BT 256          /* segment padding quantum */
#define BM 128          /* tile M */
#define BN 128          /* tile N */
#define BK 32           /* K-tile (ring-3) */
#define CAP (NT_TOK*2 + NE*BT)   /* 67584 padded assignment capacity */
#define CHUNK_ROWS 33792         /* = CAP/2: two balanced chunks, no tail */

typedef _Float16 f16x8 __attribute__((ext_vector_type(8)));
typedef float f32x4 __attribute__((ext_vector_type(4)));
typedef float f32x8 __attribute__((ext_vector_type(8)));

__device__ __forceinline__ unsigned short f2h_bits(float v){
  _Float16 h = (_Float16)v;
  return __builtin_bit_cast(unsigned short, h);
}

__device__ __forceinline__ void async16(const void* g, void* l){
  __builtin_amdgcn_global_load_lds((const __attribute__((address_space(1))) void*)g,
                                   (__attribute__((address_space(3))) void*)l, 16, 0, 0);
}

// bijective XCD-aware remap (m204 variant)
__device__ __forceinline__ int xcd_remap(int orig, int nwg){
  int q = nwg >> 3, r = nwg & 7;
  int x = orig & 7, i = orig >> 3;
  int base = (x < r) ? x*(q+1) : r*(q+1) + (x-r)*q;
  return base + i;
}

// ---------------- prep kernels ----------------

// fallback standalone cast (used only if ws can't hold XB — not on the normal path)
__global__ __launch_bounds__(256) void cvt_f16_kernel(const float* __restrict__ src,
                                                      unsigned short* __restrict__ dst, int n8){
  int i = blockIdx.x*256 + threadIdx.x;
  if (i >= n8) return;
  float4 a = ((const float4*)src)[2*i];
  float4 b = ((const float4*)src)[2*i+1];
  union { unsigned short u[8]; uint4 v; } r;
  r.u[0]=f2h_bits(a.x); r.u[1]=f2h_bits(a.y); r.u[2]=f2h_bits(a.z); r.u[3]=f2h_bits(a.w);
  r.u[4]=f2h_bits(b.x); r.u[5]=f2h_bits(b.y); r.u[6]=f2h_bits(b.z); r.u[7]=f2h_bits(b.w);
  ((uint4*)dst)[i] = r.v;
}

// src [E][R][C] f32 -> dst [E][C][R] f16 ; 64x64 tiles, float4 reads, 8B f16 writes
__global__ __launch_bounds__(256) void transpose_f16_v2(const float* __restrict__ src,
    unsigned short* __restrict__ dst, int R, int C){
  __shared__ float t[64][65];
  int ez = blockIdx.z;
  const float* s = src + (size_t)ez*R*C;
  unsigned short* d = dst + (size_t)ez*R*C;
  int c0 = blockIdx.x*64, r0 = blockIdx.y*64;
  int tx = threadIdx.x & 15, ty = threadIdx.x >> 4;
  #pragma unroll
  for (int i=0;i<4;i++){
    float4 v = *(const float4*)&s[(size_t)(r0+ty+i*16)*C + c0 + tx*4];
    t[ty+i*16][tx*4+0]=v.x; t[ty+i*16][tx*4+1]=v.y;
    t[ty+i*16][tx*4+2]=v.z; t[ty+i*16][tx*4+3]=v.w;
  }
  __syncthreads();
  #pragma unroll
  for (int i=0;i<4;i++){
    int cc = ty + i*16;                       // src col -> dst row (c0+cc)
    union { unsigned short u[4]; uint2 v; } o;
    #pragma unroll
    for (int j=0;j<4;j++) o.u[j] = f2h_bits(t[tx*4+j][cc]);
    *(uint2*)&d[(size_t)(c0+cc)*R + r0 + tx*4] = o.v;
  }
}

// ---------------- router (f64 accumulate -> top-2 selection matches np ref) ----------------
// FUSED x->f16 cast: the router already streams every element of x exactly once per token;
// XB[t][j*64+lane] = f2h(xv) replaces the standalone cvt kernel (saves 134MB re-read + launch).
// WRITE_XB=false fallback keeps the old behavior when ws has no XB.

template<bool WRITE_XB>
__global__ __launch_bounds__(256) void router_kernel(const float* __restrict__ x,
    const float* __restrict__ Wr, const float* __restrict__ br,
    int* __restrict__ topi, float* __restrict__ topw, int* __restrict__ counts,
    unsigned short* __restrict__ XB){
  __shared__ float wr_s[NE*DM];
  __shared__ int bcnt[NE];
  int tid = threadIdx.x;
  if (tid < NE) bcnt[tid] = 0;
  for (int idx=tid; idx<NE*DM; idx+=256){
    int k = idx>>3, e = idx&7;
    wr_s[e*DM + k] = Wr[idx];
  }
  __syncthreads();
  int w = tid>>6, lane = tid&63;
  for (int tt=0; tt<16; ++tt){
    int t = blockIdx.x*64 + w*16 + tt;
    const float* xr = x + (size_t)t*DM;
    double acc[NE];
    #pragma unroll
    for (int e=0;e<NE;e++) acc[e]=0.0;
    #pragma unroll
    for (int j=0;j<16;j++){
      float xv = xr[j*64 + lane];
      if (WRITE_XB) XB[(size_t)t*DM + j*64 + lane] = f2h_bits(xv);
      #pragma unroll
      for (int e=0;e<NE;e++) acc[e] += (double)xv * (double)wr_s[e*DM + j*64 + lane];
    }
    #pragma unroll
    for (int e=0;e<NE;e++){
      #pragma unroll
      for (int d=32; d; d>>=1) acc[e] += __shfl_xor(acc[e], d);
    }
    if (lane==0){
      double l[NE];
      #pragma unroll
      for (int e=0;e<NE;e++) l[e] = acc[e] + (double)br[e];
      int i0 = 0;
      #pragma unroll
      for (int e=1;e<NE;e++) if (l[e] > l[i0]) i0 = e;
      int i1 = (i0==0) ? 1 : 0;
      #pragma unroll
      for (int e=0;e<NE;e++) if (e != i0 && l[e] > l[i1]) i1 = e;
      double w0 = 1.0/(1.0 + exp(l[i1]-l[i0]));   // renormalized top-2 softmax, exact identity
      topi[2*t] = i0; topi[2*t+1] = i1;
      topw[2*t] = (float)w0; topw[2*t+1] = (float)(1.0-w0);
      atomicAdd(&bcnt[i0],1); atomicAdd(&bcnt[i1],1);   // LDS atomics
    }
  }
  __syncthreads();
  if (tid < NE && bcnt[tid] > 0) atomicAdd(&counts[tid], bcnt[tid]);
}

__global__ void offsets_kernel(const int* __restrict__ counts, int* __restrict__ off){
  if (threadIdx.x==0 && blockIdx.x==0){
    int o = 0;
    for (int e=0;e<NE;e++){ off[e] = o; o += ((counts[e]+BT-1)/BT)*BT; }
    off[NE] = o;
  }
}

// hierarchical scatter: LDS intra-block rank + one global atomic per expert per block
__global__ __launch_bounds__(256) void scatter_kernel(const int* __restrict__ topi,
    const float* __restrict__ topw, const int* __restrict__ off,
    int* __restrict__ cursor, int* __restrict__ atok, float* __restrict__ awgt){
  __shared__ int bcnt[NE];
  __shared__ int bbase[NE];
  int tid = threadIdx.x;
  if (tid < NE) bcnt[tid] = 0;
  __syncthreads();
  int t = blockIdx.x*256 + tid;
  int e0 = topi[2*t],   e1 = topi[2*t+1];
  int r0 = atomicAdd(&bcnt[e0], 1);
  int r1 = atomicAdd(&bcnt[e1], 1);
  __syncthreads();
  if (tid < NE) bbase[tid] = (bcnt[tid] > 0) ? atomicAdd(&cursor[tid], bcnt[tid]) : 0;
  __syncthreads();
  int s0 = off[e0] + bbase[e0] + r0;
  int s1 = off[e1] + bbase[e1] + r1;
  atok[s0] = t;  awgt[s0] = topw[2*t];
  atok[s1] = t;  awgt[s1] = topw[2*t+1];
}

// ---------------- 128x128 4-wave GEMM core (12 waves/CU, nt-fastest) — R17/R18 best --------
// 3 blocks/CU x 4 waves = 12 waves/CU (68 VGPR + 64 AGPR, 48KB ring-3 LDS); nt-fastest
// block order (consecutive wg share the BIG operand A panel -> L2-hit; B cache-resident).
// Ring-3: tile t in buf[t%3]; stage t+2 during t (A phase 0, B phase 1; 4 instr/tile).
// Top-of-tile: outstanding {t,t+1} = 8 -> vmcnt(4) drains tile t (oldest-first, m135);
// tail vmcnt(0). buf(t+2)=buf(t-1), freed at t's top barrier.
// LDS slot map (R11-verified, 0 conflicts): slot(r,kc)=(r>>1)*8+((kc+4*(r&1))^((r>>1)&7))

template<int KDIM, bool IS_G2>
__global__ __launch_bounds__(256, 3) void gemm_big_kernel(
    const unsigned short* __restrict__ Asrc,    // XB (g1) or Hb (g2)
    const unsigned short* __restrict__ WT,      // W1T (g1) or W2T (g2), [E][N][K] f16
    const float* __restrict__ bias,             // b1 or b2
    const int* __restrict__ atok,
    const float* __restrict__ awgt,
    const int* __restrict__ offs,
    unsigned short* __restrict__ H,             // g1 out
    float* __restrict__ out,                    // g2 out
    int c0){
  __shared__ unsigned short As[3][BM*BK];       // 3 x 8 KB
  __shared__ unsigned short Bs[3][BN*BK];       // 3 x 8 KB
  const int NDIM = IS_G2 ? DM : DH;
  const int NT = NDIM/BN;
  int wg = xcd_remap(blockIdx.x, gridDim.x);
  int nt = wg % NT, mt = wg / NT;               // nt-fastest: consecutive wg share A panel
  int total = offs[NE];
  int m0 = c0 + mt*BM;
  if (m0 >= total) return;
  int e = 0;
  #pragma unroll
  for (int q=0;q<NE-1;q++) if (m0 >= offs[q+1]) e = q+1;
  int tid = threadIdx.x;
  int lane = tid&63, wid = tid>>6;
  int wm = wid>>1, wn = wid&1;                  // 2x2 waves; per-wave out 64x64

  // staging: slot c = j*256+tid (j<2) holds G[srow][schunk]:
  //   u=(c&7)^((c>>3)&7); srow=2*(c>>3)+(u>>2); schunk=u&3   (128 rows x 4 chunks)
  const unsigned short* agp[2];
  const unsigned short* bgp[2];
  int dofs[2];
  #pragma unroll
  for (int j=0;j<2;j++){
    int c = j*256 + tid;
    int u = (c&7) ^ ((c>>3)&7);
    int srow = ((c>>3)<<1) + (u>>2);
    int sch  = u&3;
    if (IS_G2){
      agp[j] = Asrc + (size_t)(m0 - c0 + srow)*KDIM + sch*8;
    } else {
      int tok = atok[m0 + srow];
      if (tok < 0) tok = 0;                 // pad rows: safe dummy gather
      agp[j] = Asrc + (size_t)tok*KDIM + sch*8;
    }
    bgp[j] = WT + ((size_t)e*NDIM + nt*BN + srow)*KDIM + sch*8;
    dofs[j] = c*8;                          // element offset of 16B slot c
  }

  // read offsets: elem = (r>>1)*64 + ((kc + 4*(r&1)) ^ ((r>>1)&7))*8 ; +512 per 16 rows
  int pos = (((lane>>4) + ((lane&1)<<2)) ^ ((lane>>1)&7)) << 3;
  int aoff0 = (wm*32 + ((lane&15)>>1))*64 + pos;
  int boff0 = (wn*32 + ((lane&15)>>1))*64 + pos;

  f32x4 acc[4][4];
  #pragma unroll
  for (int i=0;i<4;i++)
    #pragma unroll
    for (int j=0;j<4;j++) acc[i][j] = 0.0f;

  const int NKT = KDIM/BK;
  // prologue: prime tiles 0,1 (per tile A then B — matches in-loop order)
  #pragma unroll
  for (int t=0;t<2;t++){
    #pragma unroll
    for (int j=0;j<2;j++) async16(agp[j] + t*BK, &As[t][dofs[j]]);
    #pragma unroll
    for (int j=0;j<2;j++) async16(bgp[j] + t*BK, &Bs[t][dofs[j]]);
  }

  int cur = 0;
  for (int kt=0; kt<NKT; ++kt){
    if (kt < NKT-1) asm volatile("s_waitcnt vmcnt(4)" ::: "memory");
    else            asm volatile("s_waitcnt vmcnt(0)" ::: "memory");
    __builtin_amdgcn_s_barrier();
    int nxt2 = cur + 2; if (nxt2 >= 3) nxt2 -= 3;
    const unsigned short* Ab = &As[cur][0];
    const unsigned short* Bb = &Bs[cur][0];
    f16x8 b[4], a[4];
    #pragma unroll
    for (int nf=0;nf<4;nf++) b[nf] = *(const f16x8*)&Bb[boff0 + nf*512];
    #pragma unroll
    for (int mf=0;mf<4;mf++) a[mf] = *(const f16x8*)&Ab[aoff0 + mf*512];
    if (kt+2 < NKT){
      #pragma unroll
      for (int j=0;j<2;j++) async16(agp[j] + (size_t)(kt+2)*BK, &As[nxt2][dofs[j]]);
    }
    __builtin_amdgcn_s_setprio(1);
    #pragma unroll
    for (int mf=0;mf<4;mf++)
      #pragma unroll
      for (int nf=0;nf<2;nf++)
        acc[mf][nf] = __builtin_amdgcn_mfma_f32_16x16x32_f16(a[mf], b[nf], acc[mf][nf], 0,0,0);
    __builtin_amdgcn_s_setprio(0);
    __builtin_amdgcn_s_barrier();           // mid-tile (R7/R8-measured win)
    if (kt+2 < NKT){
      #pragma unroll
      for (int j=0;j<2;j++) async16(bgp[j] + (size_t)(kt+2)*BK, &Bs[nxt2][dofs[j]]);
    }
    __builtin_amdgcn_s_setprio(1);
    #pragma unroll
    for (int mf=0;mf<4;mf++)
      #pragma unroll
      for (int nf=2;nf<4;nf++)
        acc[mf][nf] = __builtin_amdgcn_mfma_f32_16x16x32_f16(a[mf], b[nf], acc[mf][nf], 0,0,0);
    __builtin_amdgcn_s_setprio(0);
    cur = (cur + 1 == 3) ? 0 : cur + 1;
  }

  // epilogue (verified C mapping)
  int nbase = nt*BN + wn*64 + (lane&15);
  if (!IS_G2){
    const float* be = bias + (size_t)e*DH;
    int rloc = (m0 - c0) + wm*64 + ((lane>>4)<<2);
    #pragma unroll
    for (int mf=0;mf<4;mf++)
      #pragma unroll
      for (int nf=0;nf<4;nf++){
        int nn = nbase + nf*16;
        float bv = be[nn];
        #pragma unroll
        for (int r2=0;r2<4;r2++){
          float v = acc[mf][nf][r2] + bv;
          float g = 0.5f*v*(1.0f + erff(v*0.70710678118654752f));
          H[(size_t)(rloc + mf*16 + r2)*DH + nn] = f2h_bits(g);
        }
      }
  } else {
    const float* be = bias + (size_t)e*DM;
    int sbase = m0 + wm*64 + ((lane>>4)<<2);
    #pragma unroll
    for (int mf=0;mf<4;mf++){
      #pragma unroll
      for (int r2=0;r2<4;r2++){
        int slot = sbase + mf*16 + r2;
        int tok = atok[slot];
        float wgt = awgt[slot];
        if (tok >= 0){
          #pragma unroll
          for (int nf=0;nf<4;nf++){
            int nn = nbase + nf*16;
            float v = acc[mf][nf][r2] + be[nn];
            atomicAdd(&out[(size_t)tok*DM + nn], wgt*v);
          }
        }
      }
    }
  }
}

// ---------------- GEMM1 fallback (A staged from f32 x, no XB; 128x128 tile) ----------------

__global__ __launch_bounds__(256) void gemm1_f32_kernel(
    const float* __restrict__ xf, const unsigned short* __restrict__ W1T,
    const float* __restrict__ b1, const int* __restrict__ atok,
    const int* __restrict__ offs, unsigned short* __restrict__ H, int c0){
  __shared__ float Asf[128*64];
  __shared__ unsigned short Bsld[128*64];
  const int NT = DH/128;
  int wg = xcd_remap(blockIdx.x, gridDim.x);
  int nt = wg % NT, mt = wg / NT;
  int total = offs[NE];
  int m0 = c0 + mt*128;
  if (m0 >= total) return;
  int e = 0;
  #pragma unroll
  for (int q=0;q<NE-1;q++) if (m0 >= offs[q+1]) e = q+1;
  int tid = threadIdx.x;
  const void* ag[8];
  int aofs[8];
  #pragma unroll
  for (int j=0;j<8;j++){
    int c = j*256 + tid;
    int r = c>>4, sb = (c&15)*16;
    int tok = atok[m0 + r];
    if (tok < 0) tok = 0;
    ag[j] = (const void*)((const char*)(xf + (size_t)tok*DM) + sb);
    aofs[j] = c*16;
  }
  const unsigned short* bg[4];
  int bofs[4];
  #pragma unroll
  for (int j=0;j<4;j++){
    int c = j*256 + tid;
    int r = c>>3, s = c&7;
    bg[j] = W1T + ((size_t)e*DH + nt*128 + r)*DM + s*8;
    bofs[j] = c*16;
  }
  f32x4 acc[4][4];
  #pragma unroll
  for (int i=0;i<4;i++)
    #pragma unroll
    for (int j=0;j<4;j++) acc[i][j] = 0.0f;
  int lane = tid&63;
  int wm = tid>>7, wn = (tid>>6)&1;
  int arow = wm*64 + (lane&15);
  int ak0  = (lane>>4)*8;
  int brr  = (wn*64 + (lane&15))*64 + ak0;
  for (int kt=0; kt<DM/64; ++kt){
    #pragma unroll
    for (int j=0;j<8;j++)
      async16((const char*)ag[j] + (size_t)kt*64*4, (char*)Asf + aofs[j]);
    #pragma unroll
    for (int j=0;j<4;j++)
      async16(bg[j] + (size_t)kt*64, (char*)Bsld + bofs[j]);
    __syncthreads();
    #pragma unroll
    for (int kk=0; kk<64; kk+=32){
      f16x8 a[4], b[4];
      #pragma unroll
      for (int f=0;f<4;f++){
        f32x8 v = *(const f32x8*)&Asf[(arow + f*16)*64 + ak0 + kk];
        a[f] = __builtin_convertvector(v, f16x8);
        b[f] = *(const f16x8*)&Bsld[brr + f*16*64 + kk];
      }
      #pragma unroll
      for (int i=0;i<4;i++)
        #pragma unroll
        for (int j2=0;j2<4;j2++)
          acc[i][j2] = __builtin_amdgcn_mfma_f32_16x16x32_f16(a[i], b[j2], acc[i][j2], 0,0,0);
    }
    __syncthreads();
  }
  const float* b1e = b1 + (size_t)e*DH;
  int rloc = (m0 - c0) + wm*64 + ((lane>>4)<<2);
  int nbase = nt*128 + wn*64 + (lane&15);
  #pragma unroll
  for (int i=0;i<4;i++)
    #pragma unroll
    for (int j=0;j<4;j++){
      int nn = nbase + j*16;
      float bv = b1e[nn];
      #pragma unroll
      for (int r2=0;r2<4;r2++){
        float v = acc[i][j][r2] + bv;
        float g = 0.5f*v*(1.0f + erff(v*0.70710678118654752f));
        H[(size_t)(rloc + i*16 + r2)*DH + nn] = f2h_bits(g);
      }
    }
}

__global__ void fill_kernel(float* p, float v, size_t n){
  size_t i = (size_t)blockIdx.x*256 + threadIdx.x;
  if (i < n) p[i] = v;
}

// ---------------- launch ----------------

extern "C" void kernel_launch(void* const* d_in, const int* in_sizes, int n_in,
                              void* d_out, int out_size, void* d_ws, size_t ws_size,
                              hipStream_t stream){
  const float* x  = (const float*)d_in[0];
  const float* Wr = (const float*)d_in[1];
  const float* br = (const float*)d_in[2];
  const float* W1 = (const float*)d_in[3];
  const float* b1 = (const float*)d_in[4];
  const float* W2 = (const float*)d_in[5];
  const float* b2 = (const float*)d_in[6];
  float* out = (float*)d_out;

  char* ws = (char*)d_ws;
  size_t o = 0;
  auto take = [&](size_t bytes)->void*{
    void* p = ws + o; o += (bytes + 255) & ~(size_t)255; return p;
  };
  // mandatory
  unsigned short* W1T = (unsigned short*)take((size_t)NE*DM*DH*2);
  unsigned short* W2T = (unsigned short*)take((size_t)NE*DM*DH*2);
  int*   TOPI = (int*)take((size_t)NT_TOK*2*4);
  float* TOPW = (float*)take((size_t)NT_TOK*2*4);
  int*   ATOK = (int*)take((size_t)CAP*4);
  float* AWGT = (float*)take((size_t)CAP*4);
  int*   CNT  = (int*)take(256);     // counts[8] | cursor[8] | off[9]
  int* CUR = CNT + 8;
  int* OFF = CNT + 16;

  if (o + (size_t)BT*DH*2 > ws_size){
    fill_kernel<<<(unsigned)((out_size+255)/256), 256, 0, stream>>>(out, 4321.5f, (size_t)out_size);
    return;
  }

  // optional XB (f16 x)
  unsigned short* XB = nullptr;
  bool use_xb = false;
  {
    size_t xb_bytes = (size_t)NT_TOK*DM*2 + 256;
    size_t need_h  = (size_t)2048*DH*2;
    if (o + xb_bytes + need_h <= ws_size){
      use_xb = true;
      XB = (unsigned short*)take((size_t)NT_TOK*DM*2);
    }
  }
  // H chunk: as much as ws allows, up to CHUNK_ROWS (= CAP/2 -> 2 balanced chunks)
  size_t rem = ws_size - o;
  size_t cr = (rem / ((size_t)DH*2)) / BT * BT;
  if (cr > (size_t)CHUNK_ROWS) cr = CHUNK_ROWS;
  if (cr < BT){
    fill_kernel<<<(unsigned)((out_size+255)/256), 256, 0, stream>>>(out, 4321.5f, (size_t)out_size);
    return;
  }
  int CR = (int)cr;
  unsigned short* Hb = (unsigned short*)take((size_t)CR*DH*2);

  hipMemsetAsync(CNT, 0, 64, stream);
  hipMemsetAsync(ATOK, 0xFF, (size_t)CAP*4, stream);            // token = -1
  hipMemsetAsync(out, 0, (size_t)out_size*sizeof(float), stream);

  transpose_f16_v2<<<dim3(DH/64, DM/64, NE), 256, 0, stream>>>(W1, W1T, DM, DH);
  transpose_f16_v2<<<dim3(DM/64, DH/64, NE), 256, 0, stream>>>(W2, W2T, DH, DM);
  if (use_xb)
    router_kernel<true><<<NT_TOK/64, 256, 0, stream>>>(x, Wr, br, TOPI, TOPW, CNT, XB);
  else
    router_kernel<false><<<NT_TOK/64, 256, 0, stream>>>(x, Wr, br, TOPI, TOPW, CNT, nullptr);
  offsets_kernel<<<1, 1, 0, stream>>>(CNT, OFF);
  scatter_kernel<<<NT_TOK/256, 256, 0, stream>>>(TOPI, TOPW, OFF, CUR, ATOK, AWGT);

  for (int c0 = 0; c0 < CAP; c0 += CR){
    int rows = CAP - c0; if (rows > CR) rows = CR;
    int mtc = (rows + BM - 1)/BM;
    if (use_xb)
      gemm_big_kernel<DM, false><<<dim3((DH/BN)*mtc), 256, 0, stream>>>(
          XB, W1T, b1, ATOK, AWGT, OFF, Hb, out, c0);
    else
      gemm1_f32_kernel<<<dim3((DH/128)*((rows+127)/128)), 256, 0, stream>>>(
          x, W1T, b1, ATOK, OFF, Hb, c0);
    gemm_big_kernel<DH, true><<<dim3((DM/BN)*mtc), 256, 0, stream>>>(
        Hb, W2T, b2, ATOK, AWGT, OFF, Hb, out, c0);
  }
}